// Round 7
// baseline (924.147 us; speedup 1.0000x reference)
//
#include <hip/hip_runtime.h>
#include <math.h>

// DPCA2D: dual-pruned cosine-sim cross-attention.
// B=8, C=256, Nq=9216 (96x96), Nc=4096 (64x64), INNER=512, HEADS=8, D=64,
// BH=64, top-k 8x8 -> 64 kept tokens.
//
// Round 10: GEMMs with NO LDS AND NO BARRIERS. Both A and B MFMA fragments
// are loaded directly global->VGPR (lane (lc,quad) reads row*K + k0 + quad*8;
// 4 quads fill each 64B line -> fully line-efficient). R6-R9 showed every
// stage->syncthreads structure lands 139-163us (vmcnt(0) drain per K-step,
// ~2 blocks/CU convoy); floors are ~23us MFMA / ~22us HBM. Removing the
// drain lets loads pipeline across K iterations within each wave.

#define EPSN 1e-5f

typedef __attribute__((ext_vector_type(8))) short bf16x8;
typedef __attribute__((ext_vector_type(4))) float f32x4;

__device__ inline unsigned short f2bf(float f) {
    unsigned u = __float_as_uint(f);
    u += 0x7fff + ((u >> 16) & 1);          // RNE
    return (unsigned short)(u >> 16);
}
__device__ inline float bf2f(unsigned short h) {
    return __uint_as_float((unsigned)h << 16);
}

// ---------------- fp32 -> bf16 hi/lo split (weights) ----------------
__global__ __launch_bounds__(256) void cvt_split_kernel(
    const float* __restrict__ x, unsigned short* __restrict__ hi,
    unsigned short* __restrict__ lo, int n)
{
    int i = blockIdx.x * 256 + threadIdx.x;
    if (i < n) {
        float v = x[i];
        unsigned short h = f2bf(v);
        hi[i] = h;
        lo[i] = f2bf(v - bf2f(h));
    }
}
__global__ __launch_bounds__(256) void cvt_bf16_kernel(
    const float* __restrict__ x, unsigned short* __restrict__ y, int n)
{
    int i = blockIdx.x * 256 + threadIdx.x;
    if (i < n) y[i] = f2bf(x[i]);
}

// ---------------- channel LayerNorm -> transposed bf16 hi/lo ------------
__global__ __launch_bounds__(256) void chan_norm_split_kernel(
    const float* __restrict__ x, const float* __restrict__ g,
    const float* __restrict__ bb, unsigned short* __restrict__ yh,
    unsigned short* __restrict__ yl, int N)
{
    int idx = blockIdx.x * 256 + threadIdx.x;
    int b = idx / N, p = idx - b * N;
    const float* xb = x + (size_t)b * 256 * N + p;
    float mean = 0.f, m2 = 0.f;
    for (int c = 0; c < 256; ++c) {
        float v = xb[(size_t)c * N];
        mean += v; m2 += v * v;
    }
    mean *= (1.f / 256.f); m2 *= (1.f / 256.f);
    float inv = 1.f / sqrtf(m2 - mean * mean + EPSN);
    uint4* yhr = (uint4*)(yh + ((size_t)b * N + p) * 256);
    uint4* ylr = (uint4*)(yl + ((size_t)b * N + p) * 256);
    for (int c0 = 0; c0 < 256; c0 += 8) {
        unsigned short hh[8], ll[8];
        #pragma unroll
        for (int j = 0; j < 8; ++j) {
            int c = c0 + j;
            float v = (xb[(size_t)c * N] - mean) * inv * g[c] + bb[c];
            hh[j] = f2bf(v);
            ll[j] = f2bf(v - bf2f(hh[j]));
        }
        uint4 ph, pl;
        ph.x = (unsigned)hh[0] | ((unsigned)hh[1] << 16);
        ph.y = (unsigned)hh[2] | ((unsigned)hh[3] << 16);
        ph.z = (unsigned)hh[4] | ((unsigned)hh[5] << 16);
        ph.w = (unsigned)hh[6] | ((unsigned)hh[7] << 16);
        pl.x = (unsigned)ll[0] | ((unsigned)ll[1] << 16);
        pl.y = (unsigned)ll[2] | ((unsigned)ll[3] << 16);
        pl.z = (unsigned)ll[4] | ((unsigned)ll[5] << 16);
        pl.w = (unsigned)ll[6] | ((unsigned)ll[7] << 16);
        yhr[c0 >> 3] = ph;
        ylr[c0 >> 3] = pl;
    }
}

// ---------------- split-bf16 MFMA GEMM: C = A @ Bt^T (x3 passes) ---------
// MODE 0: fp32 C (z,M,N). MODE 1: q epilogue — exact col norms + qprobe from
// fp32 acc; store pre-normalized q bf16 in (bh, p, 64) p-major layout.
// No LDS, no barriers: A and B fragments direct global->VGPR. Lane (lc,quad)
// reads (row + lc)*K + k0 + quad*8 — per fragment the wave covers 16 rows x
// one full 64B line each. A is L2-hot (0.5 MB shared by all x-blocks); B has
// 4x m-block reuse through L1/L2. Loads of iteration k+1 overlap MFMAs of
// iteration k (no vmcnt(0) drain anywhere in the loop).
template <int MODE>
__global__ __launch_bounds__(256) void gemm_x3(
    const unsigned short* __restrict__ Ah, const unsigned short* __restrict__ Al,
    const unsigned short* __restrict__ Bth, const unsigned short* __restrict__ Btl,
    void* __restrict__ Cv, float* __restrict__ qprobe,
    int M, int N, int K, long long strideBt, long long strideC)
{
    const unsigned short* BzH = Bth + (size_t)blockIdx.z * strideBt;
    const unsigned short* BzL = Btl + (size_t)blockIdx.z * strideBt;
    int n0 = blockIdx.x * 128, m0 = blockIdx.y * 128;
    int t = threadIdx.x;
    int w = t >> 6, l = t & 63;
    int wm = (w >> 1) * 64, wn = (w & 1) * 64;
    int lc = l & 15, quad = l >> 4;

    f32x4 acc[4][4];
    #pragma unroll
    for (int i = 0; i < 4; ++i)
        #pragma unroll
        for (int j = 0; j < 4; ++j) acc[i][j] = {0.f, 0.f, 0.f, 0.f};

    // per-lane fragment bases (row advances by 16 per frag index, k by 32)
    const size_t astep = (size_t)16 * K;
    size_t abase = (size_t)(m0 + wm + lc) * K + quad * 8;
    size_t bbase = (size_t)(n0 + wn + lc) * K + quad * 8;

    for (int k0 = 0; k0 < K; k0 += 32) {
        bf16x8 ah[4], al_[4], bh_[4], bl_[4];
        #pragma unroll
        for (int i = 0; i < 4; ++i) {
            ah[i]  = *(const bf16x8*)(Ah + abase + (size_t)i * astep + k0);
            al_[i] = *(const bf16x8*)(Al + abase + (size_t)i * astep + k0);
        }
        #pragma unroll
        for (int j = 0; j < 4; ++j) {
            bh_[j] = *(const bf16x8*)(BzH + bbase + (size_t)j * astep + k0);
            bl_[j] = *(const bf16x8*)(BzL + bbase + (size_t)j * astep + k0);
        }
        #pragma unroll
        for (int i = 0; i < 4; ++i)
            #pragma unroll
            for (int j = 0; j < 4; ++j) {
                acc[i][j] = __builtin_amdgcn_mfma_f32_16x16x32_bf16(al_[i], bh_[j], acc[i][j], 0, 0, 0);
                acc[i][j] = __builtin_amdgcn_mfma_f32_16x16x32_bf16(ah[i],  bl_[j], acc[i][j], 0, 0, 0);
                acc[i][j] = __builtin_amdgcn_mfma_f32_16x16x32_bf16(ah[i],  bh_[j], acc[i][j], 0, 0, 0);
            }
    }

    // C/D layout: col=lane&15, row=quad*4+reg (m89-verified)
    if (MODE == 0) {
        float* C = (float*)Cv;
        size_t cbase = (size_t)blockIdx.z * strideC;
        #pragma unroll
        for (int i = 0; i < 4; ++i)
            #pragma unroll
            for (int j = 0; j < 4; ++j)
                #pragma unroll
                for (int r = 0; r < 4; ++r) {
                    int row = m0 + wm + i * 16 + quad * 4 + r;
                    int col = n0 + wn + j * 16 + lc;
                    C[cbase + (size_t)row * N + col] = acc[i][j][r];
                }
    } else {
        // wave's 64 M-rows = one head: exact column norms in-wave
        float inv[4];
        #pragma unroll
        for (int j = 0; j < 4; ++j) {
            float s = 0.f;
            #pragma unroll
            for (int i = 0; i < 4; ++i)
                #pragma unroll
                for (int r = 0; r < 4; ++r) s += acc[i][j][r] * acc[i][j][r];
            s += __shfl_xor(s, 16);
            s += __shfl_xor(s, 32);
            inv[j] = 1.f / fmaxf(sqrtf(s), 1e-12f);
        }
        // store q_n bf16, layout (bh, p, 64): 4 consecutive d per 8B store
        unsigned short* qbf = (unsigned short*)Cv;
        #pragma unroll
        for (int i = 0; i < 4; ++i) {
            int row0 = m0 + wm + i * 16 + quad * 4;
            int h = row0 >> 6, d0 = row0 & 63;
            #pragma unroll
            for (int j = 0; j < 4; ++j) {
                int col = n0 + wn + j * 16 + lc;
                size_t addr = ((size_t)(blockIdx.z * 8 + h) * 9216 + col) * 64 + d0;
                unsigned lo = (unsigned)f2bf(acc[i][j][0] * inv[j])
                            | ((unsigned)f2bf(acc[i][j][1] * inv[j]) << 16);
                unsigned hi = (unsigned)f2bf(acc[i][j][2] * inv[j])
                            | ((unsigned)f2bf(acc[i][j][3] * inv[j]) << 16);
                uint2 pk; pk.x = lo; pk.y = hi;
                *(uint2*)(qbf + addr) = pk;
            }
        }
        int bh = blockIdx.z * 8 + ((m0 + wm) >> 6);
        #pragma unroll
        for (int i = 0; i < 4; ++i)
            #pragma unroll
            for (int r = 0; r < 4; ++r) {
                float s = 0.f;
                #pragma unroll
                for (int j = 0; j < 4; ++j) s += acc[i][j][r] * inv[j];
                s += __shfl_xor(s, 1);
                s += __shfl_xor(s, 2);
                s += __shfl_xor(s, 4);
                s += __shfl_xor(s, 8);
                if (lc == 0)
                    atomicAdd(&qprobe[bh * 64 + i * 16 + quad * 4 + r], s);
            }
    }
}

// ---------------- plain bf16 MFMA GEMM (out projection) ------------------
// No LDS, no barriers: A and B fragments direct global->VGPR.
__global__ __launch_bounds__(256) void gemm_mfma(
    const unsigned short* __restrict__ A, const unsigned short* __restrict__ Bt,
    float* __restrict__ C, int M, int N, int K,
    long long strideBt, long long strideC)
{
    const unsigned short* Bz = Bt + (size_t)blockIdx.z * strideBt;
    int n0 = blockIdx.x * 128, m0 = blockIdx.y * 128;
    int t = threadIdx.x;
    int w = t >> 6, l = t & 63;
    int wm = (w >> 1) * 64, wn = (w & 1) * 64;
    int lc = l & 15, quad = l >> 4;
    f32x4 acc[4][4];
    #pragma unroll
    for (int i = 0; i < 4; ++i)
        #pragma unroll
        for (int j = 0; j < 4; ++j) acc[i][j] = {0.f, 0.f, 0.f, 0.f};

    const size_t astep = (size_t)16 * K;
    size_t abase = (size_t)(m0 + wm + lc) * K + quad * 8;
    size_t bbase = (size_t)(n0 + wn + lc) * K + quad * 8;

    for (int k0 = 0; k0 < K; k0 += 32) {
        bf16x8 af[4], bfr[4];
        #pragma unroll
        for (int i = 0; i < 4; ++i)
            af[i] = *(const bf16x8*)(A + abase + (size_t)i * astep + k0);
        #pragma unroll
        for (int j = 0; j < 4; ++j)
            bfr[j] = *(const bf16x8*)(Bz + bbase + (size_t)j * astep + k0);
        #pragma unroll
        for (int i = 0; i < 4; ++i)
            #pragma unroll
            for (int j = 0; j < 4; ++j)
                acc[i][j] = __builtin_amdgcn_mfma_f32_16x16x32_bf16(af[i], bfr[j], acc[i][j], 0, 0, 0);
    }

    size_t cbase = (size_t)blockIdx.z * strideC;
    #pragma unroll
    for (int i = 0; i < 4; ++i)
        #pragma unroll
        for (int j = 0; j < 4; ++j)
            #pragma unroll
            for (int r = 0; r < 4; ++r) {
                int row = m0 + wm + i * 16 + quad * 4 + r;
                int col = n0 + wn + j * 16 + lc;
                C[cbase + (size_t)row * N + col] = acc[i][j][r];
            }
}

// ---------------- l2 inverse norm (fp32 k) ----------------
__global__ __launch_bounds__(256) void l2inv_f32_kernel(
    const float* __restrict__ x, float* __restrict__ inv, int N,
    long long strideB, long long strideH)
{
    int idx = blockIdx.x * 256 + threadIdx.x;
    int bh = idx / N, p = idx - bh * N;
    const float* base = x + (size_t)(bh >> 3) * strideB + (size_t)(bh & 7) * strideH + p;
    float ss = 0.f;
    #pragma unroll 8
    for (int d = 0; d < 64; ++d) { float v = base[(size_t)d * N]; ss += v * v; }
    inv[idx] = 1.f / fmaxf(sqrtf(ss), 1e-12f);
}

// ---------------- row/col sums of |k_n| per bh ---------------------------
__global__ __launch_bounds__(256) void krowcol_kernel(
    const float* __restrict__ k, const float* __restrict__ invnk,
    float* __restrict__ krow, float* __restrict__ kcol)
{
    int bh = blockIdx.x, b = bh >> 3, h = bh & 7;
    int d0 = blockIdx.y * 8;
    const float* kbase = k + ((size_t)b * 512 + (size_t)h * 64) * 4096;
    __shared__ float inv_s[4096];
    __shared__ float tile[64 * 65];
    int t = threadIdx.x;
    for (int l = t; l < 4096; l += 256) inv_s[l] = invnk[(size_t)bh * 4096 + l];
    for (int dd = 0; dd < 8; ++dd) {
        int d = d0 + dd;
        __syncthreads();
        for (int l = t; l < 4096; l += 256)
            tile[(l >> 6) * 65 + (l & 63)] = kbase[(size_t)d * 4096 + l];
        __syncthreads();
        if (t < 64) {
            float s = 0.f;
            for (int ww = 0; ww < 64; ++ww) s += fabsf(tile[t * 65 + ww]) * inv_s[t * 64 + ww];
            krow[((size_t)bh * 64 + d) * 64 + t] = s;
        } else if (t < 128) {
            int ww = t - 64;
            float s = 0.f;
            for (int hh = 0; hh < 64; ++hh) s += fabsf(tile[hh * 65 + ww]) * inv_s[hh * 64 + ww];
            kcol[((size_t)bh * 64 + d) * 64 + ww] = s;
        }
    }
}

// ---------------- top-8 row/col selection per bh -------------------------
__global__ void topk_kernel(const float* __restrict__ qprobe,
                            const float* __restrict__ krow,
                            const float* __restrict__ kcol,
                            int* __restrict__ toph, int* __restrict__ topw)
{
    int bh = blockIdx.x, t = threadIdx.x;  // 64 threads
    __shared__ float qp[64], sr[64], sc[64];
    qp[t] = qprobe[bh * 64 + t];
    __syncthreads();
    float s1 = 0.f, s2 = 0.f;
    for (int d = 0; d < 64; ++d) {
        float qv = qp[d];
        s1 += qv * krow[((size_t)bh * 64 + d) * 64 + t];
        s2 += qv * kcol[((size_t)bh * 64 + d) * 64 + t];
    }
    sr[t] = s1; sc[t] = s2;
    __syncthreads();
    if (t == 0) {
        unsigned long long used = 0ull;
        for (int it = 0; it < 8; ++it) {
            int best = -1; float bv = -INFINITY;
            for (int i = 0; i < 64; ++i)
                if (!((used >> i) & 1ull) && sr[i] > bv) { bv = sr[i]; best = i; }
            if (best < 0) best = it;
            used |= 1ull << best;
            toph[bh * 8 + it] = best;
        }
        used = 0ull;
        for (int it = 0; it < 8; ++it) {
            int best = -1; float bv = -INFINITY;
            for (int i = 0; i < 64; ++i)
                if (!((used >> i) & 1ull) && sc[i] > bv) { bv = sc[i]; best = i; }
            if (best < 0) best = it;
            used |= 1ull << best;
            topw[bh * 8 + it] = best;
        }
    }
}

// ---------------- gather pruned normalized K -> bf16 [bh][t][d] ----------
__global__ __launch_bounds__(256) void gather_k_kernel(
    const float* __restrict__ k, const float* __restrict__ invnk,
    const int* __restrict__ toph, const int* __restrict__ topw,
    unsigned short* __restrict__ ksel)
{
    int bh = blockIdx.x, b = bh >> 3, h = bh & 7;
    __shared__ int th_s[8], tw_s[8];
    if (threadIdx.x < 8) th_s[threadIdx.x] = toph[bh * 8 + threadIdx.x];
    else if (threadIdx.x < 16) tw_s[threadIdx.x - 8] = topw[bh * 8 + threadIdx.x - 8];
    __syncthreads();
    const float* kbase = k + ((size_t)b * 512 + (size_t)h * 64) * 4096;
    for (int l = threadIdx.x; l < 4096; l += 256) {
        int tok = l >> 6, d = l & 63;
        int p = th_s[tok >> 3] * 64 + tw_s[tok & 7];
        ksel[(size_t)bh * 4096 + l] = f2bf(kbase[(size_t)d * 4096 + p] * invnk[(size_t)bh * 4096 + p]);
    }
}

// ---------------- V at gathered positions -> bf16 transposed [bh][d][t] --
__global__ __launch_bounds__(256) void vsel_kernel(
    const float* __restrict__ w_kv, const unsigned short* __restrict__ ctxt,
    const int* __restrict__ toph, const int* __restrict__ topw,
    unsigned short* __restrict__ vt)
{
    int bh = blockIdx.x, b = bh >> 3, h = bh & 7;
    __shared__ int th_s[8], tw_s[8];
    if (threadIdx.x < 8) th_s[threadIdx.x] = toph[bh * 8 + threadIdx.x];
    else if (threadIdx.x < 16) tw_s[threadIdx.x - 8] = topw[bh * 8 + threadIdx.x - 8];
    __syncthreads();
    const unsigned short* cb = ctxt + (size_t)b * 4096 * 256;
    int l = blockIdx.y * 1024 + threadIdx.x;
    for (int it = 0; it < 4; ++it, l += 256) {
        int tok = l >> 6, d = l & 63;
        int p = th_s[tok >> 3] * 64 + tw_s[tok & 7];
        const float* wr = w_kv + (size_t)(512 + h * 64 + d) * 256;
        const unsigned short* cr = cb + (size_t)p * 256;
        float s = 0.f;
        for (int c = 0; c < 256; ++c) s += wr[c] * bf2f(cr[c]);
        vt[(size_t)bh * 4096 + d * 64 + tok] = f2bf(s);
    }
}

// ---------------- MFMA flash-style attention ------------------------------
// q_pd: (bh, 9216, 64) bf16 pre-normalized. ksel: (bh,64t,64d). vt: (bh,64d,64t).
// attn_t: (b, 9216, 512) bf16. Block = 4 waves x 16 p = 64 p, grid (144, 64).
// Fixed softmax shift 1.0 (unit q,k -> sim <= 1).
#define LPAD 72
__global__ __launch_bounds__(256) void attn_mfma_kernel(
    const unsigned short* __restrict__ q_pd, const unsigned short* __restrict__ ksel,
    const unsigned short* __restrict__ vt, unsigned short* __restrict__ attn_t)
{
    int bh = blockIdx.y, b = bh >> 3, h = bh & 7;
    __shared__ unsigned short Ks[64 * LPAD];      // [t][d]
    __shared__ unsigned short Vs[64 * LPAD];      // [d][t]
    __shared__ unsigned short Ps[4][16 * LPAD];   // per-wave [p][t]
    int t = threadIdx.x, w = t >> 6, l = t & 63;
    int lc = l & 15, quad = l >> 4;
    // stage K,V (padded rows, 16B chunks): 512 chunks over 256 threads x2
    {
        int r0 = t >> 3, c0 = (t & 7) * 8;        // rows 0..31
        const unsigned short* kg = ksel + (size_t)bh * 4096;
        const unsigned short* vg = vt + (size_t)bh * 4096;
        *(uint4*)(Ks + r0 * LPAD + c0)        = *(const uint4*)(kg + r0 * 64 + c0);
        *(uint4*)(Ks + (r0 + 32) * LPAD + c0) = *(const uint4*)(kg + (r0 + 32) * 64 + c0);
        *(uint4*)(Vs + r0 * LPAD + c0)        = *(const uint4*)(vg + r0 * 64 + c0);
        *(uint4*)(Vs + (r0 + 32) * LPAD + c0) = *(const uint4*)(vg + (r0 + 32) * 64 + c0);
    }
    __syncthreads();
    int p0 = blockIdx.x * 64 + w * 16;
    // Q fragments: A[m=p][k=d] contiguous from (bh,p,64)
    const unsigned short* qrow = q_pd + ((size_t)bh * 9216 + p0 + lc) * 64;
    bf16x8 aq0 = *(const bf16x8*)(qrow + quad * 8);
    bf16x8 aq1 = *(const bf16x8*)(qrow + 32 + quad * 8);
    // sim = Q K^T  (M=p, N=t, K=d)
    f32x4 sacc[4];
    #pragma unroll
    for (int j = 0; j < 4; ++j) sacc[j] = {0.f, 0.f, 0.f, 0.f};
    #pragma unroll
    for (int j = 0; j < 4; ++j) {
        bf16x8 bk0 = *(const bf16x8*)(Ks + (j * 16 + lc) * LPAD + quad * 8);
        bf16x8 bk1 = *(const bf16x8*)(Ks + (j * 16 + lc) * LPAD + 32 + quad * 8);
        sacc[j] = __builtin_amdgcn_mfma_f32_16x16x32_bf16(aq0, bk0, sacc[j], 0, 0, 0);
        sacc[j] = __builtin_amdgcn_mfma_f32_16x16x32_bf16(aq1, bk1, sacc[j], 0, 0, 0);
    }
    // exp + per-row denom (row p = quad*4+r, col t = j*16+lc)
    float e[4][4], den[4] = {0.f, 0.f, 0.f, 0.f};
    #pragma unroll
    for (int j = 0; j < 4; ++j)
        #pragma unroll
        for (int r = 0; r < 4; ++r) {
            float v = __expf(sacc[j][r] - 1.f);
            e[j][r] = v; den[r] += v;
        }
    #pragma unroll
    for (int r = 0; r < 4; ++r) {
        den[r] += __shfl_xor(den[r], 1);
        den[r] += __shfl_xor(den[r], 2);
        den[r] += __shfl_xor(den[r], 4);
        den[r] += __shfl_xor(den[r], 8);
    }
    // P (C-layout) -> LDS -> A-layout
    #pragma unroll
    for (int j = 0; j < 4; ++j)
        #pragma unroll
        for (int r = 0; r < 4; ++r)
            Ps[w][(quad * 4 + r) * LPAD + j * 16 + lc] = f2bf(e[j][r]);
    __syncthreads();
    bf16x8 ap0 = *(const bf16x8*)(Ps[w] + lc * LPAD + quad * 8);
    bf16x8 ap1 = *(const bf16x8*)(Ps[w] + lc * LPAD + 32 + quad * 8);
    // O = P V  (M=p, N=d, K=t)
    f32x4 oacc[4];
    #pragma unroll
    for (int j = 0; j < 4; ++j) oacc[j] = {0.f, 0.f, 0.f, 0.f};
    #pragma unroll
    for (int j = 0; j < 4; ++j) {
        bf16x8 bv0 = *(const bf16x8*)(Vs + (j * 16 + lc) * LPAD + quad * 8);
        bf16x8 bv1 = *(const bf16x8*)(Vs + (j * 16 + lc) * LPAD + 32 + quad * 8);
        oacc[j] = __builtin_amdgcn_mfma_f32_16x16x32_bf16(ap0, bv0, oacc[j], 0, 0, 0);
        oacc[j] = __builtin_amdgcn_mfma_f32_16x16x32_bf16(ap1, bv1, oacc[j], 0, 0, 0);
    }
    float rd[4];
    #pragma unroll
    for (int r = 0; r < 4; ++r) rd[r] = 1.f / den[r];
    // store: row p = quad*4+r (same quad/r as den), col d = j*16+lc
    #pragma unroll
    for (int j = 0; j < 4; ++j)
        #pragma unroll
        for (int r = 0; r < 4; ++r) {
            int p = p0 + quad * 4 + r;
            int d = j * 16 + lc;
            attn_t[((size_t)b * 9216 + p) * 512 + h * 64 + d] = f2bf(oacc[j][r] * rd[r]);
        }
}

// ---------------- final: chan_norm + gamma*out + residual (in-place) -----
__global__ __launch_bounds__(256) void final_kernel(
    const float* __restrict__ g, const float* __restrict__ bb,
    const float* __restrict__ gamma, const float* __restrict__ qsrc,
    float* __restrict__ out)
{
    int idx = blockIdx.x * 256 + threadIdx.x;  // b*9216 + p
    int b = idx / 9216, p = idx - b * 9216;
    float* xb = out + (size_t)b * 256 * 9216 + p;
    float mean = 0.f, m2 = 0.f;
    for (int c = 0; c < 256; ++c) {
        float v = xb[(size_t)c * 9216];
        mean += v; m2 += v * v;
    }
    mean *= (1.f / 256.f); m2 *= (1.f / 256.f);
    float inv = 1.f / sqrtf(m2 - mean * mean + EPSN);
    float gm = gamma[0];
    const float* qs = qsrc + (size_t)b * 256 * 9216 + p;
    for (int c = 0; c < 256; ++c) {
        float v = (xb[(size_t)c * 9216] - mean) * inv * g[c] + bb[c];
        xb[(size_t)c * 9216] = gm * v + qs[(size_t)c * 9216];
    }
}

extern "C" void kernel_launch(void* const* d_in, const int* in_sizes, int n_in,
                              void* d_out, int out_size, void* d_ws, size_t ws_size,
                              hipStream_t stream) {
    const float* qsrc  = (const float*)d_in[0];
    const float* ctx   = (const float*)d_in[1];
    const float* qs_g  = (const float*)d_in[2];
    const float* qs_b  = (const float*)d_in[3];
    const float* ctx_g = (const float*)d_in[4];
    const float* ctx_b = (const float*)d_in[5];
    const float* out_g = (const float*)d_in[6];
    const float* out_b = (const float*)d_in[7];
    const float* w_q   = (const float*)d_in[8];
    const float* w_kv  = (const float*)d_in[9];
    const float* w_out = (const float*)d_in[10];
    const float* gamma = (const float*)d_in[11];
    float* out = (float*)d_out;

    // ---- workspace (bytes), peak ~190 MB, liveness-aliased ----
    // Region A @0 (75,497,472): qs_h+qs_l [1-2]; k_f fp32 [4-8]; attn_t [10-11]
    // Region B @75,497,472 (75,497,472): q_pd bf16 (bh,9216,64) [2-10]
    // Region C @150,994,944 (33,554,432): ctx_h+ctx_l [3-9]
    char* base = (char*)d_ws;
    unsigned short* qs_h  = (unsigned short*)(base + 0);
    unsigned short* qs_l  = (unsigned short*)(base + 37748736);
    float*          k_f   = (float*)        (base + 0);
    unsigned short* attn_t= (unsigned short*)(base + 0);
    unsigned short* q_pd  = (unsigned short*)(base + 75497472);
    unsigned short* ctx_h = (unsigned short*)(base + 150994944);
    unsigned short* ctx_l = (unsigned short*)(base + 167772160);
    char* S = base + 184549376;
    float* invnk = (float*)S;                     S += 262144 * 4;
    float* krow  = (float*)S;                     S += 262144 * 4;
    float* kcol  = (float*)S;                     S += 262144 * 4;
    float* qprob = (float*)S;                     S += 4096 * 4;
    unsigned short* ksel = (unsigned short*)S;    S += 262144 * 2;
    unsigned short* vt   = (unsigned short*)S;    S += 262144 * 2;
    int*   toph  = (int*)S;                       S += 512 * 4;
    int*   topw  = (int*)S;                       S += 512 * 4;
    unsigned short* wq_h = (unsigned short*)S;    S += 131072 * 2;
    unsigned short* wq_l = (unsigned short*)S;    S += 131072 * 2;
    unsigned short* wk_h = (unsigned short*)S;    S += 131072 * 2;
    unsigned short* wk_l = (unsigned short*)S;    S += 131072 * 2;
    unsigned short* wo_h = (unsigned short*)S;    S += 131072 * 2;

    // 0. weight splits
    cvt_split_kernel<<<512, 256, 0, stream>>>(w_q, wq_h, wq_l, 131072);
    cvt_split_kernel<<<512, 256, 0, stream>>>(w_kv, wk_h, wk_l, 131072);
    cvt_bf16_kernel<<<512, 256, 0, stream>>>(w_out, wo_h, 131072);
    hipMemsetAsync(qprob, 0, 4096 * sizeof(float), stream);
    // 1. qs hi/lo = chan_norm(query_source)^T
    chan_norm_split_kernel<<<288, 256, 0, stream>>>(qsrc, qs_g, qs_b, qs_h, qs_l, 9216);
    // 2. q = w_q @ qs (bf16x3) -> q_pd (bh,p,64) + qprobe (fused epilogue)
    gemm_x3<1><<<dim3(72, 4, 8), 256, 0, stream>>>(
        wq_h, wq_l, qs_h, qs_l, q_pd, qprob, 512, 9216, 256,
        9216LL * 256, 0);
    // 3. ctx hi/lo = chan_norm(context)^T
    chan_norm_split_kernel<<<128, 256, 0, stream>>>(ctx, ctx_g, ctx_b, ctx_h, ctx_l, 4096);
    // 4. k = w_kv[0:512] @ ctx (bf16x3) -> fp32 (qs region dead)
    gemm_x3<0><<<dim3(32, 4, 8), 256, 0, stream>>>(
        wk_h, wk_l, ctx_h, ctx_l, k_f, nullptr, 512, 4096, 256,
        4096LL * 256, 512LL * 4096);
    // 5. inverse l2 norms of k
    l2inv_f32_kernel<<<1024, 256, 0, stream>>>(k_f, invnk, 4096, 512LL * 4096, 64LL * 4096);
    // 6. |k_n| row/col marginals
    krowcol_kernel<<<dim3(64, 8), 256, 0, stream>>>(k_f, invnk, krow, kcol);
    // 7. top-8 rows/cols
    topk_kernel<<<64, 64, 0, stream>>>(qprob, krow, kcol, toph, topw);
    // 8. gather pruned normalized K -> bf16 [t][d]
    gather_k_kernel<<<64, 256, 0, stream>>>(k_f, invnk, toph, topw, ksel);
    // 9. V at gathered positions -> bf16 [d][t]
    vsel_kernel<<<dim3(64, 4), 256, 0, stream>>>(w_kv, ctx_h, toph, topw, vt);
    // 10. MFMA attention -> attn_t bf16 (b,9216,512) (k dead)
    attn_mfma_kernel<<<dim3(144, 64), 256, 0, stream>>>(q_pd, ksel, vt, attn_t);
    // 11. out_pre = w_out @ attn -> fp32 d_out
    gemm_mfma<<<dim3(72, 2, 8), 256, 0, stream>>>(
        wo_h, attn_t, out, 256, 9216, 512, 9216LL * 512, 256LL * 9216);
    // 12. final chan_norm + gamma*out + residual, in-place on d_out
    final_kernel<<<288, 256, 0, stream>>>(out_g, out_b, gamma, qsrc, out);
}

// Round 8
// 720.209 us; speedup vs baseline: 1.2832x; 1.2832x over previous
//
#include <hip/hip_runtime.h>
#include <math.h>

// DPCA2D: dual-pruned cosine-sim cross-attention.
// B=8, C=256, Nq=9216 (96x96), Nc=4096 (64x64), INNER=512, HEADS=8, D=64,
// BH=64, top-k 8x8 -> 64 kept tokens.
//
// Round 11: (a) gemm_x3 reverted to the measured-best R0 structure (139us;
// all 5 structural variants R6-R10 were neutral-to-worse — plateau is not
// K-loop-structural). (b) out-projection + final chan_norm + residual FUSED:
// gemm_out_fused uses a 256Mx64N tile (4 waves stacked in M = full channel
// axis per block), computes per-column mean/var via shfl quad-reduce +
// cross-wave LDS reduce, applies norm+gamma+residual in-register, writes
// d_out directly. Eliminates final_kernel's 150MB round-trip + a launch.

#define EPSN 1e-5f

typedef __attribute__((ext_vector_type(8))) short bf16x8;
typedef __attribute__((ext_vector_type(4))) float f32x4;

__device__ inline unsigned short f2bf(float f) {
    unsigned u = __float_as_uint(f);
    u += 0x7fff + ((u >> 16) & 1);          // RNE
    return (unsigned short)(u >> 16);
}
__device__ inline float bf2f(unsigned short h) {
    return __uint_as_float((unsigned)h << 16);
}

#define GL2LDS(g, s) __builtin_amdgcn_global_load_lds( \
    (const __attribute__((address_space(1))) void*)(g), \
    (__attribute__((address_space(3))) void*)(s), 16, 0, 0)

// ---------------- fp32 -> bf16 hi/lo split (weights) ----------------
__global__ __launch_bounds__(256) void cvt_split_kernel(
    const float* __restrict__ x, unsigned short* __restrict__ hi,
    unsigned short* __restrict__ lo, int n)
{
    int i = blockIdx.x * 256 + threadIdx.x;
    if (i < n) {
        float v = x[i];
        unsigned short h = f2bf(v);
        hi[i] = h;
        lo[i] = f2bf(v - bf2f(h));
    }
}
__global__ __launch_bounds__(256) void cvt_bf16_kernel(
    const float* __restrict__ x, unsigned short* __restrict__ y, int n)
{
    int i = blockIdx.x * 256 + threadIdx.x;
    if (i < n) y[i] = f2bf(x[i]);
}

// ---------------- channel LayerNorm -> transposed bf16 hi/lo ------------
__global__ __launch_bounds__(256) void chan_norm_split_kernel(
    const float* __restrict__ x, const float* __restrict__ g,
    const float* __restrict__ bb, unsigned short* __restrict__ yh,
    unsigned short* __restrict__ yl, int N)
{
    int idx = blockIdx.x * 256 + threadIdx.x;
    int b = idx / N, p = idx - b * N;
    const float* xb = x + (size_t)b * 256 * N + p;
    float mean = 0.f, m2 = 0.f;
    for (int c = 0; c < 256; ++c) {
        float v = xb[(size_t)c * N];
        mean += v; m2 += v * v;
    }
    mean *= (1.f / 256.f); m2 *= (1.f / 256.f);
    float inv = 1.f / sqrtf(m2 - mean * mean + EPSN);
    uint4* yhr = (uint4*)(yh + ((size_t)b * N + p) * 256);
    uint4* ylr = (uint4*)(yl + ((size_t)b * N + p) * 256);
    for (int c0 = 0; c0 < 256; c0 += 8) {
        unsigned short hh[8], ll[8];
        #pragma unroll
        for (int j = 0; j < 8; ++j) {
            int c = c0 + j;
            float v = (xb[(size_t)c * N] - mean) * inv * g[c] + bb[c];
            hh[j] = f2bf(v);
            ll[j] = f2bf(v - bf2f(hh[j]));
        }
        uint4 ph, pl;
        ph.x = (unsigned)hh[0] | ((unsigned)hh[1] << 16);
        ph.y = (unsigned)hh[2] | ((unsigned)hh[3] << 16);
        ph.z = (unsigned)hh[4] | ((unsigned)hh[5] << 16);
        ph.w = (unsigned)hh[6] | ((unsigned)hh[7] << 16);
        pl.x = (unsigned)ll[0] | ((unsigned)ll[1] << 16);
        pl.y = (unsigned)ll[2] | ((unsigned)ll[3] << 16);
        pl.z = (unsigned)ll[4] | ((unsigned)ll[5] << 16);
        pl.w = (unsigned)ll[6] | ((unsigned)ll[7] << 16);
        yhr[c0 >> 3] = ph;
        ylr[c0 >> 3] = pl;
    }
}

// ---------------- split-bf16 MFMA GEMM: C = A @ Bt^T (x3 passes) ---------
// MODE 0: fp32 C (z,M,N). MODE 1: q epilogue — exact col norms + qprobe from
// fp32 acc; store pre-normalized q bf16 in (bh, p, 64) p-major layout.
// R0 structure (measured best: 139us): single-buffer LDS, linear staging.
template <int MODE>
__global__ __launch_bounds__(256) void gemm_x3(
    const unsigned short* __restrict__ Ah, const unsigned short* __restrict__ Al,
    const unsigned short* __restrict__ Bth, const unsigned short* __restrict__ Btl,
    void* __restrict__ Cv, float* __restrict__ qprobe,
    int M, int N, int K, long long strideBt, long long strideC)
{
    __shared__ unsigned short AsH[128 * 32], AsL[128 * 32];
    __shared__ unsigned short BsH[128 * 32], BsL[128 * 32];
    const unsigned short* BzH = Bth + (size_t)blockIdx.z * strideBt;
    const unsigned short* BzL = Btl + (size_t)blockIdx.z * strideBt;
    int n0 = blockIdx.x * 128, m0 = blockIdx.y * 128;
    int t = threadIdx.x;
    int w = t >> 6, l = t & 63;
    int wm = (w >> 1) * 64, wn = (w & 1) * 64;
    int lc = l & 15, quad = l >> 4;

    f32x4 acc[4][4];
    #pragma unroll
    for (int i = 0; i < 4; ++i)
        #pragma unroll
        for (int j = 0; j < 4; ++j) acc[i][j] = {0.f, 0.f, 0.f, 0.f};

    int srow = t >> 2;
    int sseg = (t & 3) * 8;
    for (int k0 = 0; k0 < K; k0 += 32) {
        size_t a0 = (size_t)(m0 + srow) * K + k0 + sseg;
        size_t a1 = (size_t)(m0 + 64 + srow) * K + k0 + sseg;
        size_t b0 = (size_t)(n0 + srow) * K + k0 + sseg;
        size_t b1 = (size_t)(n0 + 64 + srow) * K + k0 + sseg;
        __syncthreads();
        GL2LDS(Ah + a0, AsH + (size_t)t * 8);
        GL2LDS(Ah + a1, AsH + 2048 + (size_t)t * 8);
        GL2LDS(Al + a0, AsL + (size_t)t * 8);
        GL2LDS(Al + a1, AsL + 2048 + (size_t)t * 8);
        GL2LDS(BzH + b0, BsH + (size_t)t * 8);
        GL2LDS(BzH + b1, BsH + 2048 + (size_t)t * 8);
        GL2LDS(BzL + b0, BsL + (size_t)t * 8);
        GL2LDS(BzL + b1, BsL + 2048 + (size_t)t * 8);
        __syncthreads();
        bf16x8 ah[4], al_[4], bh_[4], bl_[4];
        #pragma unroll
        for (int i = 0; i < 4; ++i) {
            ah[i]  = *(const bf16x8*)(AsH + (size_t)(wm + i * 16 + lc) * 32 + quad * 8);
            al_[i] = *(const bf16x8*)(AsL + (size_t)(wm + i * 16 + lc) * 32 + quad * 8);
        }
        #pragma unroll
        for (int j = 0; j < 4; ++j) {
            bh_[j] = *(const bf16x8*)(BsH + (size_t)(wn + j * 16 + lc) * 32 + quad * 8);
            bl_[j] = *(const bf16x8*)(BsL + (size_t)(wn + j * 16 + lc) * 32 + quad * 8);
        }
        #pragma unroll
        for (int i = 0; i < 4; ++i)
            #pragma unroll
            for (int j = 0; j < 4; ++j) {
                acc[i][j] = __builtin_amdgcn_mfma_f32_16x16x32_bf16(al_[i], bh_[j], acc[i][j], 0, 0, 0);
                acc[i][j] = __builtin_amdgcn_mfma_f32_16x16x32_bf16(ah[i],  bl_[j], acc[i][j], 0, 0, 0);
                acc[i][j] = __builtin_amdgcn_mfma_f32_16x16x32_bf16(ah[i],  bh_[j], acc[i][j], 0, 0, 0);
            }
    }
    // C/D layout: col=lane&15, row=quad*4+reg (m89-verified)
    if (MODE == 0) {
        float* C = (float*)Cv;
        size_t cbase = (size_t)blockIdx.z * strideC;
        #pragma unroll
        for (int i = 0; i < 4; ++i)
            #pragma unroll
            for (int j = 0; j < 4; ++j)
                #pragma unroll
                for (int r = 0; r < 4; ++r) {
                    int row = m0 + wm + i * 16 + quad * 4 + r;
                    int col = n0 + wn + j * 16 + lc;
                    C[cbase + (size_t)row * N + col] = acc[i][j][r];
                }
    } else {
        // wave's 64 M-rows = one head: exact column norms in-wave
        float inv[4];
        #pragma unroll
        for (int j = 0; j < 4; ++j) {
            float s = 0.f;
            #pragma unroll
            for (int i = 0; i < 4; ++i)
                #pragma unroll
                for (int r = 0; r < 4; ++r) s += acc[i][j][r] * acc[i][j][r];
            s += __shfl_xor(s, 16);
            s += __shfl_xor(s, 32);
            inv[j] = 1.f / fmaxf(sqrtf(s), 1e-12f);
        }
        // store q_n bf16, layout (bh, p, 64): 4 consecutive d per 8B store
        unsigned short* qbf = (unsigned short*)Cv;
        #pragma unroll
        for (int i = 0; i < 4; ++i) {
            int row0 = m0 + wm + i * 16 + quad * 4;
            int h = row0 >> 6, d0 = row0 & 63;
            #pragma unroll
            for (int j = 0; j < 4; ++j) {
                int col = n0 + wn + j * 16 + lc;
                size_t addr = ((size_t)(blockIdx.z * 8 + h) * 9216 + col) * 64 + d0;
                unsigned lo = (unsigned)f2bf(acc[i][j][0] * inv[j])
                            | ((unsigned)f2bf(acc[i][j][1] * inv[j]) << 16);
                unsigned hi = (unsigned)f2bf(acc[i][j][2] * inv[j])
                            | ((unsigned)f2bf(acc[i][j][3] * inv[j]) << 16);
                uint2 pk; pk.x = lo; pk.y = hi;
                *(uint2*)(qbf + addr) = pk;
            }
        }
        int bh = blockIdx.z * 8 + ((m0 + wm) >> 6);
        #pragma unroll
        for (int i = 0; i < 4; ++i)
            #pragma unroll
            for (int r = 0; r < 4; ++r) {
                float s = 0.f;
                #pragma unroll
                for (int j = 0; j < 4; ++j) s += acc[i][j][r] * inv[j];
                s += __shfl_xor(s, 1);
                s += __shfl_xor(s, 2);
                s += __shfl_xor(s, 4);
                s += __shfl_xor(s, 8);
                if (lc == 0)
                    atomicAdd(&qprobe[bh * 64 + i * 16 + quad * 4 + r], s);
            }
    }
}

// ---------------- fused out-projection + chan_norm + residual ------------
// out_pre = wo @ attn  (M=256 channels, N=9216 tokens, K=512), then per
// column: mean/var over the 256 channels, out = norm*g+b, final = gamma*out
// + qsrc. Tile 256M x 64N: wave w owns rows w*64..w*64+63; block owns the
// FULL channel axis -> norm reduces entirely in-block. Writes d_out directly.
__global__ __launch_bounds__(256) void gemm_out_fused(
    const unsigned short* __restrict__ A,   // wo_h [256][512] bf16
    const unsigned short* __restrict__ Bt,  // attn_t (b,9216,512) bf16
    const float* __restrict__ g, const float* __restrict__ bb,
    const float* __restrict__ gamma, const float* __restrict__ qsrc,
    float* __restrict__ out)
{
    __shared__ unsigned short As[256 * 32];   // 16 KB
    __shared__ unsigned short Bs[64 * 32];    // 4 KB
    __shared__ float2 colred[4][64];          // 2 KB
    int b = blockIdx.z;
    const unsigned short* Bz = Bt + (size_t)b * 9216 * 512;
    int n0 = blockIdx.x * 64;
    int t = threadIdx.x;
    int w = t >> 6, l = t & 63;
    int lc = l & 15, quad = l >> 4;

    f32x4 acc[4][4];
    #pragma unroll
    for (int i = 0; i < 4; ++i)
        #pragma unroll
        for (int j = 0; j < 4; ++j) acc[i][j] = {0.f, 0.f, 0.f, 0.f};

    int srow = t >> 2, sseg = (t & 3) * 8;
    for (int k0 = 0; k0 < 512; k0 += 32) {
        __syncthreads();
        #pragma unroll
        for (int s = 0; s < 4; ++s)
            GL2LDS(A + (size_t)(s * 64 + srow) * 512 + k0 + sseg,
                   As + (size_t)s * 2048 + (size_t)t * 8);
        GL2LDS(Bz + (size_t)(n0 + srow) * 512 + k0 + sseg, Bs + (size_t)t * 8);
        __syncthreads();
        bf16x8 af[4], bfr[4];
        #pragma unroll
        for (int i = 0; i < 4; ++i)
            af[i] = *(const bf16x8*)(As + (size_t)(w * 64 + i * 16 + lc) * 32 + quad * 8);
        #pragma unroll
        for (int j = 0; j < 4; ++j)
            bfr[j] = *(const bf16x8*)(Bs + (size_t)(j * 16 + lc) * 32 + quad * 8);
        #pragma unroll
        for (int i = 0; i < 4; ++i)
            #pragma unroll
            for (int j = 0; j < 4; ++j)
                acc[i][j] = __builtin_amdgcn_mfma_f32_16x16x32_bf16(af[i], bfr[j], acc[i][j], 0, 0, 0);
    }

    // per-column (token) sums over this wave's 64 channels
    // column of lane = j*16+lc; rows = w*64 + i*16 + quad*4 + r
    float s_[4], ss_[4];
    #pragma unroll
    for (int j = 0; j < 4; ++j) {
        float s = 0.f, ss = 0.f;
        #pragma unroll
        for (int i = 0; i < 4; ++i)
            #pragma unroll
            for (int r = 0; r < 4; ++r) {
                float v = acc[i][j][r];
                s += v; ss += v * v;
            }
        s  += __shfl_xor(s, 16);  s  += __shfl_xor(s, 32);
        ss += __shfl_xor(ss, 16); ss += __shfl_xor(ss, 32);
        s_[j] = s; ss_[j] = ss;
    }
    if (quad == 0) {
        #pragma unroll
        for (int j = 0; j < 4; ++j) {
            colred[w][j * 16 + lc].x = s_[j];
            colred[w][j * 16 + lc].y = ss_[j];
        }
    }
    __syncthreads();
    float mean[4], inv[4];
    #pragma unroll
    for (int j = 0; j < 4; ++j) {
        float ts = 0.f, tss = 0.f;
        #pragma unroll
        for (int ww = 0; ww < 4; ++ww) {
            float2 v = colred[ww][j * 16 + lc];
            ts += v.x; tss += v.y;
        }
        float m = ts * (1.f / 256.f);
        float var = tss * (1.f / 256.f) - m * m;
        mean[j] = m;
        inv[j] = 1.f / sqrtf(var + EPSN);
    }
    float gm = gamma[0];
    const float* qsb = qsrc + (size_t)b * 256 * 9216;
    float* ob = out + (size_t)b * 256 * 9216;
    #pragma unroll
    for (int i = 0; i < 4; ++i)
        #pragma unroll
        for (int r = 0; r < 4; ++r) {
            int row = w * 64 + i * 16 + quad * 4 + r;
            float gg = g[row], bv = bb[row];
            #pragma unroll
            for (int j = 0; j < 4; ++j) {
                int col = n0 + j * 16 + lc;
                float v = (acc[i][j][r] - mean[j]) * inv[j] * gg + bv;
                ob[(size_t)row * 9216 + col] = gm * v + qsb[(size_t)row * 9216 + col];
            }
        }
}

// ---------------- l2 inverse norm (fp32 k) ----------------
__global__ __launch_bounds__(256) void l2inv_f32_kernel(
    const float* __restrict__ x, float* __restrict__ inv, int N,
    long long strideB, long long strideH)
{
    int idx = blockIdx.x * 256 + threadIdx.x;
    int bh = idx / N, p = idx - bh * N;
    const float* base = x + (size_t)(bh >> 3) * strideB + (size_t)(bh & 7) * strideH + p;
    float ss = 0.f;
    #pragma unroll 8
    for (int d = 0; d < 64; ++d) { float v = base[(size_t)d * N]; ss += v * v; }
    inv[idx] = 1.f / fmaxf(sqrtf(ss), 1e-12f);
}

// ---------------- row/col sums of |k_n| per bh ---------------------------
__global__ __launch_bounds__(256) void krowcol_kernel(
    const float* __restrict__ k, const float* __restrict__ invnk,
    float* __restrict__ krow, float* __restrict__ kcol)
{
    int bh = blockIdx.x, b = bh >> 3, h = bh & 7;
    int d0 = blockIdx.y * 8;
    const float* kbase = k + ((size_t)b * 512 + (size_t)h * 64) * 4096;
    __shared__ float inv_s[4096];
    __shared__ float tile[64 * 65];
    int t = threadIdx.x;
    for (int l = t; l < 4096; l += 256) inv_s[l] = invnk[(size_t)bh * 4096 + l];
    for (int dd = 0; dd < 8; ++dd) {
        int d = d0 + dd;
        __syncthreads();
        for (int l = t; l < 4096; l += 256)
            tile[(l >> 6) * 65 + (l & 63)] = kbase[(size_t)d * 4096 + l];
        __syncthreads();
        if (t < 64) {
            float s = 0.f;
            for (int ww = 0; ww < 64; ++ww) s += fabsf(tile[t * 65 + ww]) * inv_s[t * 64 + ww];
            krow[((size_t)bh * 64 + d) * 64 + t] = s;
        } else if (t < 128) {
            int ww = t - 64;
            float s = 0.f;
            for (int hh = 0; hh < 64; ++hh) s += fabsf(tile[hh * 65 + ww]) * inv_s[hh * 64 + ww];
            kcol[((size_t)bh * 64 + d) * 64 + ww] = s;
        }
    }
}

// ---------------- top-8 row/col selection per bh -------------------------
__global__ void topk_kernel(const float* __restrict__ qprobe,
                            const float* __restrict__ krow,
                            const float* __restrict__ kcol,
                            int* __restrict__ toph, int* __restrict__ topw)
{
    int bh = blockIdx.x, t = threadIdx.x;  // 64 threads
    __shared__ float qp[64], sr[64], sc[64];
    qp[t] = qprobe[bh * 64 + t];
    __syncthreads();
    float s1 = 0.f, s2 = 0.f;
    for (int d = 0; d < 64; ++d) {
        float qv = qp[d];
        s1 += qv * krow[((size_t)bh * 64 + d) * 64 + t];
        s2 += qv * kcol[((size_t)bh * 64 + d) * 64 + t];
    }
    sr[t] = s1; sc[t] = s2;
    __syncthreads();
    if (t == 0) {
        unsigned long long used = 0ull;
        for (int it = 0; it < 8; ++it) {
            int best = -1; float bv = -INFINITY;
            for (int i = 0; i < 64; ++i)
                if (!((used >> i) & 1ull) && sr[i] > bv) { bv = sr[i]; best = i; }
            if (best < 0) best = it;
            used |= 1ull << best;
            toph[bh * 8 + it] = best;
        }
        used = 0ull;
        for (int it = 0; it < 8; ++it) {
            int best = -1; float bv = -INFINITY;
            for (int i = 0; i < 64; ++i)
                if (!((used >> i) & 1ull) && sc[i] > bv) { bv = sc[i]; best = i; }
            if (best < 0) best = it;
            used |= 1ull << best;
            topw[bh * 8 + it] = best;
        }
    }
}

// ---------------- gather pruned normalized K -> bf16 [bh][t][d] ----------
__global__ __launch_bounds__(256) void gather_k_kernel(
    const float* __restrict__ k, const float* __restrict__ invnk,
    const int* __restrict__ toph, const int* __restrict__ topw,
    unsigned short* __restrict__ ksel)
{
    int bh = blockIdx.x, b = bh >> 3, h = bh & 7;
    __shared__ int th_s[8], tw_s[8];
    if (threadIdx.x < 8) th_s[threadIdx.x] = toph[bh * 8 + threadIdx.x];
    else if (threadIdx.x < 16) tw_s[threadIdx.x - 8] = topw[bh * 8 + threadIdx.x - 8];
    __syncthreads();
    const float* kbase = k + ((size_t)b * 512 + (size_t)h * 64) * 4096;
    for (int l = threadIdx.x; l < 4096; l += 256) {
        int tok = l >> 6, d = l & 63;
        int p = th_s[tok >> 3] * 64 + tw_s[tok & 7];
        ksel[(size_t)bh * 4096 + l] = f2bf(kbase[(size_t)d * 4096 + p] * invnk[(size_t)bh * 4096 + p]);
    }
}

// ---------------- V at gathered positions -> bf16 transposed [bh][d][t] --
__global__ __launch_bounds__(256) void vsel_kernel(
    const float* __restrict__ w_kv, const unsigned short* __restrict__ ctxt,
    const int* __restrict__ toph, const int* __restrict__ topw,
    unsigned short* __restrict__ vt)
{
    int bh = blockIdx.x, b = bh >> 3, h = bh & 7;
    __shared__ int th_s[8], tw_s[8];
    if (threadIdx.x < 8) th_s[threadIdx.x] = toph[bh * 8 + threadIdx.x];
    else if (threadIdx.x < 16) tw_s[threadIdx.x - 8] = topw[bh * 8 + threadIdx.x - 8];
    __syncthreads();
    const unsigned short* cb = ctxt + (size_t)b * 4096 * 256;
    int l = blockIdx.y * 1024 + threadIdx.x;
    for (int it = 0; it < 4; ++it, l += 256) {
        int tok = l >> 6, d = l & 63;
        int p = th_s[tok >> 3] * 64 + tw_s[tok & 7];
        const float* wr = w_kv + (size_t)(512 + h * 64 + d) * 256;
        const unsigned short* cr = cb + (size_t)p * 256;
        float s = 0.f;
        for (int c = 0; c < 256; ++c) s += wr[c] * bf2f(cr[c]);
        vt[(size_t)bh * 4096 + d * 64 + tok] = f2bf(s);
    }
}

// ---------------- MFMA flash-style attention ------------------------------
// q_pd: (bh, 9216, 64) bf16 pre-normalized. ksel: (bh,64t,64d). vt: (bh,64d,64t).
// attn_t: (b, 9216, 512) bf16. Block = 4 waves x 16 p = 64 p, grid (144, 64).
// Fixed softmax shift 1.0 (unit q,k -> sim <= 1).
#define LPAD 72
__global__ __launch_bounds__(256) void attn_mfma_kernel(
    const unsigned short* __restrict__ q_pd, const unsigned short* __restrict__ ksel,
    const unsigned short* __restrict__ vt, unsigned short* __restrict__ attn_t)
{
    int bh = blockIdx.y, b = bh >> 3, h = bh & 7;
    __shared__ unsigned short Ks[64 * LPAD];      // [t][d]
    __shared__ unsigned short Vs[64 * LPAD];      // [d][t]
    __shared__ unsigned short Ps[4][16 * LPAD];   // per-wave [p][t]
    int t = threadIdx.x, w = t >> 6, l = t & 63;
    int lc = l & 15, quad = l >> 4;
    // stage K,V (padded rows, 16B chunks): 512 chunks over 256 threads x2
    {
        int r0 = t >> 3, c0 = (t & 7) * 8;        // rows 0..31
        const unsigned short* kg = ksel + (size_t)bh * 4096;
        const unsigned short* vg = vt + (size_t)bh * 4096;
        *(uint4*)(Ks + r0 * LPAD + c0)        = *(const uint4*)(kg + r0 * 64 + c0);
        *(uint4*)(Ks + (r0 + 32) * LPAD + c0) = *(const uint4*)(kg + (r0 + 32) * 64 + c0);
        *(uint4*)(Vs + r0 * LPAD + c0)        = *(const uint4*)(vg + r0 * 64 + c0);
        *(uint4*)(Vs + (r0 + 32) * LPAD + c0) = *(const uint4*)(vg + (r0 + 32) * 64 + c0);
    }
    __syncthreads();
    int p0 = blockIdx.x * 64 + w * 16;
    // Q fragments: A[m=p][k=d] contiguous from (bh,p,64)
    const unsigned short* qrow = q_pd + ((size_t)bh * 9216 + p0 + lc) * 64;
    bf16x8 aq0 = *(const bf16x8*)(qrow + quad * 8);
    bf16x8 aq1 = *(const bf16x8*)(qrow + 32 + quad * 8);
    // sim = Q K^T  (M=p, N=t, K=d)
    f32x4 sacc[4];
    #pragma unroll
    for (int j = 0; j < 4; ++j) sacc[j] = {0.f, 0.f, 0.f, 0.f};
    #pragma unroll
    for (int j = 0; j < 4; ++j) {
        bf16x8 bk0 = *(const bf16x8*)(Ks + (j * 16 + lc) * LPAD + quad * 8);
        bf16x8 bk1 = *(const bf16x8*)(Ks + (j * 16 + lc) * LPAD + 32 + quad * 8);
        sacc[j] = __builtin_amdgcn_mfma_f32_16x16x32_bf16(aq0, bk0, sacc[j], 0, 0, 0);
        sacc[j] = __builtin_amdgcn_mfma_f32_16x16x32_bf16(aq1, bk1, sacc[j], 0, 0, 0);
    }
    // exp + per-row denom (row p = quad*4+r, col t = j*16+lc)
    float e[4][4], den[4] = {0.f, 0.f, 0.f, 0.f};
    #pragma unroll
    for (int j = 0; j < 4; ++j)
        #pragma unroll
        for (int r = 0; r < 4; ++r) {
            float v = __expf(sacc[j][r] - 1.f);
            e[j][r] = v; den[r] += v;
        }
    #pragma unroll
    for (int r = 0; r < 4; ++r) {
        den[r] += __shfl_xor(den[r], 1);
        den[r] += __shfl_xor(den[r], 2);
        den[r] += __shfl_xor(den[r], 4);
        den[r] += __shfl_xor(den[r], 8);
    }
    // P (C-layout) -> LDS -> A-layout
    #pragma unroll
    for (int j = 0; j < 4; ++j)
        #pragma unroll
        for (int r = 0; r < 4; ++r)
            Ps[w][(quad * 4 + r) * LPAD + j * 16 + lc] = f2bf(e[j][r]);
    __syncthreads();
    bf16x8 ap0 = *(const bf16x8*)(Ps[w] + lc * LPAD + quad * 8);
    bf16x8 ap1 = *(const bf16x8*)(Ps[w] + lc * LPAD + 32 + quad * 8);
    // O = P V  (M=p, N=d, K=t)
    f32x4 oacc[4];
    #pragma unroll
    for (int j = 0; j < 4; ++j) oacc[j] = {0.f, 0.f, 0.f, 0.f};
    #pragma unroll
    for (int j = 0; j < 4; ++j) {
        bf16x8 bv0 = *(const bf16x8*)(Vs + (j * 16 + lc) * LPAD + quad * 8);
        bf16x8 bv1 = *(const bf16x8*)(Vs + (j * 16 + lc) * LPAD + 32 + quad * 8);
        oacc[j] = __builtin_amdgcn_mfma_f32_16x16x32_bf16(ap0, bv0, oacc[j], 0, 0, 0);
        oacc[j] = __builtin_amdgcn_mfma_f32_16x16x32_bf16(ap1, bv1, oacc[j], 0, 0, 0);
    }
    float rd[4];
    #pragma unroll
    for (int r = 0; r < 4; ++r) rd[r] = 1.f / den[r];
    // store: row p = quad*4+r (same quad/r as den), col d = j*16+lc
    #pragma unroll
    for (int j = 0; j < 4; ++j)
        #pragma unroll
        for (int r = 0; r < 4; ++r) {
            int p = p0 + quad * 4 + r;
            int d = j * 16 + lc;
            attn_t[((size_t)b * 9216 + p) * 512 + h * 64 + d] = f2bf(oacc[j][r] * rd[r]);
        }
}

extern "C" void kernel_launch(void* const* d_in, const int* in_sizes, int n_in,
                              void* d_out, int out_size, void* d_ws, size_t ws_size,
                              hipStream_t stream) {
    const float* qsrc  = (const float*)d_in[0];
    const float* ctx   = (const float*)d_in[1];
    const float* qs_g  = (const float*)d_in[2];
    const float* qs_b  = (const float*)d_in[3];
    const float* ctx_g = (const float*)d_in[4];
    const float* ctx_b = (const float*)d_in[5];
    const float* out_g = (const float*)d_in[6];
    const float* out_b = (const float*)d_in[7];
    const float* w_q   = (const float*)d_in[8];
    const float* w_kv  = (const float*)d_in[9];
    const float* w_out = (const float*)d_in[10];
    const float* gamma = (const float*)d_in[11];
    float* out = (float*)d_out;

    // ---- workspace (bytes), peak ~190 MB, liveness-aliased ----
    // Region A @0 (75,497,472): qs_h+qs_l [1-2]; k_f fp32 [4-8]; attn_t [10-11]
    // Region B @75,497,472 (75,497,472): q_pd bf16 (bh,9216,64) [2-10]
    // Region C @150,994,944 (33,554,432): ctx_h+ctx_l [3-9]
    char* base = (char*)d_ws;
    unsigned short* qs_h  = (unsigned short*)(base + 0);
    unsigned short* qs_l  = (unsigned short*)(base + 37748736);
    float*          k_f   = (float*)        (base + 0);
    unsigned short* attn_t= (unsigned short*)(base + 0);
    unsigned short* q_pd  = (unsigned short*)(base + 75497472);
    unsigned short* ctx_h = (unsigned short*)(base + 150994944);
    unsigned short* ctx_l = (unsigned short*)(base + 167772160);
    char* S = base + 184549376;
    float* invnk = (float*)S;                     S += 262144 * 4;
    float* krow  = (float*)S;                     S += 262144 * 4;
    float* kcol  = (float*)S;                     S += 262144 * 4;
    float* qprob = (float*)S;                     S += 4096 * 4;
    unsigned short* ksel = (unsigned short*)S;    S += 262144 * 2;
    unsigned short* vt   = (unsigned short*)S;    S += 262144 * 2;
    int*   toph  = (int*)S;                       S += 512 * 4;
    int*   topw  = (int*)S;                       S += 512 * 4;
    unsigned short* wq_h = (unsigned short*)S;    S += 131072 * 2;
    unsigned short* wq_l = (unsigned short*)S;    S += 131072 * 2;
    unsigned short* wk_h = (unsigned short*)S;    S += 131072 * 2;
    unsigned short* wk_l = (unsigned short*)S;    S += 131072 * 2;
    unsigned short* wo_h = (unsigned short*)S;    S += 131072 * 2;

    // 0. weight splits
    cvt_split_kernel<<<512, 256, 0, stream>>>(w_q, wq_h, wq_l, 131072);
    cvt_split_kernel<<<512, 256, 0, stream>>>(w_kv, wk_h, wk_l, 131072);
    cvt_bf16_kernel<<<512, 256, 0, stream>>>(w_out, wo_h, 131072);
    hipMemsetAsync(qprob, 0, 4096 * sizeof(float), stream);
    // 1. qs hi/lo = chan_norm(query_source)^T
    chan_norm_split_kernel<<<288, 256, 0, stream>>>(qsrc, qs_g, qs_b, qs_h, qs_l, 9216);
    // 2. q = w_q @ qs (bf16x3) -> q_pd (bh,p,64) + qprobe (fused epilogue)
    gemm_x3<1><<<dim3(72, 4, 8), 256, 0, stream>>>(
        wq_h, wq_l, qs_h, qs_l, q_pd, qprob, 512, 9216, 256,
        9216LL * 256, 0);
    // 3. ctx hi/lo = chan_norm(context)^T
    chan_norm_split_kernel<<<128, 256, 0, stream>>>(ctx, ctx_g, ctx_b, ctx_h, ctx_l, 4096);
    // 4. k = w_kv[0:512] @ ctx (bf16x3) -> fp32 (qs region dead)
    gemm_x3<0><<<dim3(32, 4, 8), 256, 0, stream>>>(
        wk_h, wk_l, ctx_h, ctx_l, k_f, nullptr, 512, 4096, 256,
        4096LL * 256, 512LL * 4096);
    // 5. inverse l2 norms of k
    l2inv_f32_kernel<<<1024, 256, 0, stream>>>(k_f, invnk, 4096, 512LL * 4096, 64LL * 4096);
    // 6. |k_n| row/col marginals
    krowcol_kernel<<<dim3(64, 8), 256, 0, stream>>>(k_f, invnk, krow, kcol);
    // 7. top-8 rows/cols
    topk_kernel<<<64, 64, 0, stream>>>(qprob, krow, kcol, toph, topw);
    // 8. gather pruned normalized K -> bf16 [t][d]
    gather_k_kernel<<<64, 256, 0, stream>>>(k_f, invnk, toph, topw, ksel);
    // 9. V at gathered positions -> bf16 [d][t]
    vsel_kernel<<<dim3(64, 4), 256, 0, stream>>>(w_kv, ctx_h, toph, topw, vt);
    // 10. MFMA attention -> attn_t bf16 (b,9216,512) (k dead)
    attn_mfma_kernel<<<dim3(144, 64), 256, 0, stream>>>(q_pd, ksel, vt, attn_t);
    // 11. fused: out = chan_norm(w_out @ attn)*gamma + qsrc  (direct to d_out)
    gemm_out_fused<<<dim3(144, 1, 8), 256, 0, stream>>>(
        wo_h, attn_t, out_g, out_b, gamma, qsrc, out);
}

// Round 10
// 694.136 us; speedup vs baseline: 1.3314x; 1.0376x over previous
//
#include <hip/hip_runtime.h>
#include <math.h>

// DPCA2D: dual-pruned cosine-sim cross-attention.
// B=8, C=256, Nq=9216 (96x96), Nc=4096 (64x64), INNER=512, HEADS=8, D=64,
// BH=64, top-k 8x8 -> 64 kept tokens.
//
// Round 13: R12's bf16 marginals flipped top-8 picks (absmax 0.338). Fix:
// marginals computed fp32-EXACT inside the k-GEMM epilogue. Each wave's 64
// cols = one image-row th x all tw, rows = one head's full d: krow written
// direct (shfl reduce, exclusive); kcol via 2-wave LDS combine -> 32-seg
// partial buffer -> kcolred sum. kn bf16 still feeds gather/attention
// (identical values to R11). kmarg deleted. R11's fused out-proj kept.

#define EPSN 1e-5f

typedef __attribute__((ext_vector_type(8))) short bf16x8;
typedef __attribute__((ext_vector_type(4))) float f32x4;

__device__ inline unsigned short f2bf(float f) {
    unsigned u = __float_as_uint(f);
    u += 0x7fff + ((u >> 16) & 1);          // RNE
    return (unsigned short)(u >> 16);
}
__device__ inline float bf2f(unsigned short h) {
    return __uint_as_float((unsigned)h << 16);
}

#define GL2LDS(g, s) __builtin_amdgcn_global_load_lds( \
    (const __attribute__((address_space(1))) void*)(g), \
    (__attribute__((address_space(3))) void*)(s), 16, 0, 0)

// ---------------- fp32 -> bf16 hi/lo split (weights) ----------------
__global__ __launch_bounds__(256) void cvt_split_kernel(
    const float* __restrict__ x, unsigned short* __restrict__ hi,
    unsigned short* __restrict__ lo, int n)
{
    int i = blockIdx.x * 256 + threadIdx.x;
    if (i < n) {
        float v = x[i];
        unsigned short h = f2bf(v);
        hi[i] = h;
        lo[i] = f2bf(v - bf2f(h));
    }
}
__global__ __launch_bounds__(256) void cvt_bf16_kernel(
    const float* __restrict__ x, unsigned short* __restrict__ y, int n)
{
    int i = blockIdx.x * 256 + threadIdx.x;
    if (i < n) y[i] = f2bf(x[i]);
}

// ---------------- channel LayerNorm -> transposed bf16 hi/lo ------------
__global__ __launch_bounds__(256) void chan_norm_split_kernel(
    const float* __restrict__ x, const float* __restrict__ g,
    const float* __restrict__ bb, unsigned short* __restrict__ yh,
    unsigned short* __restrict__ yl, int N)
{
    int idx = blockIdx.x * 256 + threadIdx.x;
    int b = idx / N, p = idx - b * N;
    const float* xb = x + (size_t)b * 256 * N + p;
    float mean = 0.f, m2 = 0.f;
    for (int c = 0; c < 256; ++c) {
        float v = xb[(size_t)c * N];
        mean += v; m2 += v * v;
    }
    mean *= (1.f / 256.f); m2 *= (1.f / 256.f);
    float inv = 1.f / sqrtf(m2 - mean * mean + EPSN);
    uint4* yhr = (uint4*)(yh + ((size_t)b * N + p) * 256);
    uint4* ylr = (uint4*)(yl + ((size_t)b * N + p) * 256);
    for (int c0 = 0; c0 < 256; c0 += 8) {
        unsigned short hh[8], ll[8];
        #pragma unroll
        for (int j = 0; j < 8; ++j) {
            int c = c0 + j;
            float v = (xb[(size_t)c * N] - mean) * inv * g[c] + bb[c];
            hh[j] = f2bf(v);
            ll[j] = f2bf(v - bf2f(hh[j]));
        }
        uint4 ph, pl;
        ph.x = (unsigned)hh[0] | ((unsigned)hh[1] << 16);
        ph.y = (unsigned)hh[2] | ((unsigned)hh[3] << 16);
        ph.z = (unsigned)hh[4] | ((unsigned)hh[5] << 16);
        ph.w = (unsigned)hh[6] | ((unsigned)hh[7] << 16);
        pl.x = (unsigned)ll[0] | ((unsigned)ll[1] << 16);
        pl.y = (unsigned)ll[2] | ((unsigned)ll[3] << 16);
        pl.z = (unsigned)ll[4] | ((unsigned)ll[5] << 16);
        pl.w = (unsigned)ll[6] | ((unsigned)ll[7] << 16);
        yhr[c0 >> 3] = ph;
        ylr[c0 >> 3] = pl;
    }
}

// ---------------- split-bf16 MFMA GEMM: C = A @ Bt^T (x3 passes) ---------
// Both modes: exact col l2-norms from fp32 acc, store pre-normalized bf16
// (bh, p, 64). MODE 1 (q): + qprobe atomics. MODE 2 (k): + fp32 marginals —
// krow direct (wave owns one th x full d), kcolp via 2-wave LDS combine.
// R0 K-loop structure (measured best across 5 variants: 139us).
template <int MODE>
__global__ __launch_bounds__(256) void gemm_x3(
    const unsigned short* __restrict__ Ah, const unsigned short* __restrict__ Al,
    const unsigned short* __restrict__ Bth, const unsigned short* __restrict__ Btl,
    void* __restrict__ Cv, float* __restrict__ qprobe,
    float* __restrict__ krow, float* __restrict__ kcolp,
    int M, int N, int K, long long strideBt)
{
    __shared__ unsigned short SMEM[4 * 128 * 32];   // 32 KB staging / colbuf
    unsigned short* AsH = SMEM;
    unsigned short* AsL = SMEM + 4096;
    unsigned short* BsH = SMEM + 8192;
    unsigned short* BsL = SMEM + 12288;
    const unsigned short* BzH = Bth + (size_t)blockIdx.z * strideBt;
    const unsigned short* BzL = Btl + (size_t)blockIdx.z * strideBt;
    int n0 = blockIdx.x * 128, m0 = blockIdx.y * 128;
    int t = threadIdx.x;
    int w = t >> 6, l = t & 63;
    int wm = (w >> 1) * 64, wn = (w & 1) * 64;
    int lc = l & 15, quad = l >> 4;

    f32x4 acc[4][4];
    #pragma unroll
    for (int i = 0; i < 4; ++i)
        #pragma unroll
        for (int j = 0; j < 4; ++j) acc[i][j] = {0.f, 0.f, 0.f, 0.f};

    int srow = t >> 2;
    int sseg = (t & 3) * 8;
    for (int k0 = 0; k0 < K; k0 += 32) {
        size_t a0 = (size_t)(m0 + srow) * K + k0 + sseg;
        size_t a1 = (size_t)(m0 + 64 + srow) * K + k0 + sseg;
        size_t b0 = (size_t)(n0 + srow) * K + k0 + sseg;
        size_t b1 = (size_t)(n0 + 64 + srow) * K + k0 + sseg;
        __syncthreads();
        GL2LDS(Ah + a0, AsH + (size_t)t * 8);
        GL2LDS(Ah + a1, AsH + 2048 + (size_t)t * 8);
        GL2LDS(Al + a0, AsL + (size_t)t * 8);
        GL2LDS(Al + a1, AsL + 2048 + (size_t)t * 8);
        GL2LDS(BzH + b0, BsH + (size_t)t * 8);
        GL2LDS(BzH + b1, BsH + 2048 + (size_t)t * 8);
        GL2LDS(BzL + b0, BsL + (size_t)t * 8);
        GL2LDS(BzL + b1, BsL + 2048 + (size_t)t * 8);
        __syncthreads();
        bf16x8 ah[4], al_[4], bh_[4], bl_[4];
        #pragma unroll
        for (int i = 0; i < 4; ++i) {
            ah[i]  = *(const bf16x8*)(AsH + (size_t)(wm + i * 16 + lc) * 32 + quad * 8);
            al_[i] = *(const bf16x8*)(AsL + (size_t)(wm + i * 16 + lc) * 32 + quad * 8);
        }
        #pragma unroll
        for (int j = 0; j < 4; ++j) {
            bh_[j] = *(const bf16x8*)(BsH + (size_t)(wn + j * 16 + lc) * 32 + quad * 8);
            bl_[j] = *(const bf16x8*)(BsL + (size_t)(wn + j * 16 + lc) * 32 + quad * 8);
        }
        #pragma unroll
        for (int i = 0; i < 4; ++i)
            #pragma unroll
            for (int j = 0; j < 4; ++j) {
                acc[i][j] = __builtin_amdgcn_mfma_f32_16x16x32_bf16(al_[i], bh_[j], acc[i][j], 0, 0, 0);
                acc[i][j] = __builtin_amdgcn_mfma_f32_16x16x32_bf16(ah[i],  bl_[j], acc[i][j], 0, 0, 0);
                acc[i][j] = __builtin_amdgcn_mfma_f32_16x16x32_bf16(ah[i],  bh_[j], acc[i][j], 0, 0, 0);
            }
    }
    // C/D layout: col=lane&15, row=quad*4+reg (m89-verified)
    // wave's 64 M-rows = one head: exact column l2-norms in-wave
    float inv[4];
    #pragma unroll
    for (int j = 0; j < 4; ++j) {
        float s = 0.f;
        #pragma unroll
        for (int i = 0; i < 4; ++i)
            #pragma unroll
            for (int r = 0; r < 4; ++r) s += acc[i][j][r] * acc[i][j][r];
        s += __shfl_xor(s, 16);
        s += __shfl_xor(s, 32);
        inv[j] = 1.f / fmaxf(sqrtf(s), 1e-12f);
    }
    // store normalized bf16, layout (bh, p, 64): 4 consecutive d per 8B store
    unsigned short* qbf = (unsigned short*)Cv;
    #pragma unroll
    for (int i = 0; i < 4; ++i) {
        int row0 = m0 + wm + i * 16 + quad * 4;
        int h = row0 >> 6, d0 = row0 & 63;
        #pragma unroll
        for (int j = 0; j < 4; ++j) {
            int col = n0 + wn + j * 16 + lc;
            size_t addr = ((size_t)(blockIdx.z * 8 + h) * N + col) * 64 + d0;
            unsigned lo = (unsigned)f2bf(acc[i][j][0] * inv[j])
                        | ((unsigned)f2bf(acc[i][j][1] * inv[j]) << 16);
            unsigned hi = (unsigned)f2bf(acc[i][j][2] * inv[j])
                        | ((unsigned)f2bf(acc[i][j][3] * inv[j]) << 16);
            uint2 pk; pk.x = lo; pk.y = hi;
            *(uint2*)(qbf + addr) = pk;
        }
    }
    if (MODE == 1) {
        int bh = blockIdx.z * 8 + ((m0 + wm) >> 6);
        #pragma unroll
        for (int i = 0; i < 4; ++i)
            #pragma unroll
            for (int r = 0; r < 4; ++r) {
                float s = 0.f;
                #pragma unroll
                for (int j = 0; j < 4; ++j) s += acc[i][j][r] * inv[j];
                s += __shfl_xor(s, 1);
                s += __shfl_xor(s, 2);
                s += __shfl_xor(s, 4);
                s += __shfl_xor(s, 8);
                if (lc == 0)
                    atomicAdd(&qprobe[bh * 64 + i * 16 + quad * 4 + r], s);
            }
    }
    if (MODE == 2) {
        // fp32-exact |k_n| marginals. This wave: one th = (n0+wn)>>6, all tw.
        int bx = blockIdx.x;
        int th = (n0 + wn) >> 6;
        int headbase = m0 >> 6;             // blockIdx.y * 2
        int hh = w >> 1;                    // head within block (0/1)
        int bh = blockIdx.z * 8 + headbase + hh;
        // krow[bh][d][th] = sum_tw |kn|  (lane-local over j, shfl over lc)
        #pragma unroll
        for (int i = 0; i < 4; ++i)
            #pragma unroll
            for (int r = 0; r < 4; ++r) {
                float rs = 0.f;
                #pragma unroll
                for (int j = 0; j < 4; ++j) rs += fabsf(acc[i][j][r]) * inv[j];
                rs += __shfl_xor(rs, 1);
                rs += __shfl_xor(rs, 2);
                rs += __shfl_xor(rs, 4);
                rs += __shfl_xor(rs, 8);
                if (lc == 0) {
                    int d = i * 16 + quad * 4 + r;
                    krow[((size_t)bh * 64 + d) * 64 + th] = rs;
                }
            }
        // kcolp[bh][bx][d][tw]: combine this head's 2 waves (th pair) in LDS
        float* colbuf = (float*)SMEM;       // [2 heads][64 d][64 tw] = 32 KB
        __syncthreads();
        if ((w & 1) == 0) {
            #pragma unroll
            for (int i = 0; i < 4; ++i)
                #pragma unroll
                for (int j = 0; j < 4; ++j)
                    #pragma unroll
                    for (int r = 0; r < 4; ++r)
                        colbuf[(hh * 64 + i * 16 + quad * 4 + r) * 64 + j * 16 + lc]
                            = fabsf(acc[i][j][r]) * inv[j];
        }
        __syncthreads();
        if ((w & 1) == 1) {
            #pragma unroll
            for (int i = 0; i < 4; ++i)
                #pragma unroll
                for (int j = 0; j < 4; ++j)
                    #pragma unroll
                    for (int r = 0; r < 4; ++r)
                        colbuf[(hh * 64 + i * 16 + quad * 4 + r) * 64 + j * 16 + lc]
                            += fabsf(acc[i][j][r]) * inv[j];
        }
        __syncthreads();
        for (int e = t; e < 8192; e += 256) {
            int hh2 = e >> 12, rem = e & 4095;
            int bh2 = blockIdx.z * 8 + headbase + hh2;
            kcolp[((size_t)bh2 * 32 + bx) * 4096 + rem] = colbuf[e];
        }
    }
}

// ---------------- reduce 32 kcol partials -> kcol [bh][d][tw] ------------
__global__ __launch_bounds__(256) void kcolred_kernel(
    const float* __restrict__ kcolp, float* __restrict__ kcol)
{
    int bh = blockIdx.x;
    int idx = blockIdx.y * 256 + threadIdx.x;   // d*64+tw in 0..4095
    float s = 0.f;
    #pragma unroll 8
    for (int bx = 0; bx < 32; ++bx)
        s += kcolp[((size_t)bh * 32 + bx) * 4096 + idx];
    kcol[(size_t)bh * 4096 + idx] = s;
}

// ---------------- fused out-projection + chan_norm + residual ------------
__global__ __launch_bounds__(256) void gemm_out_fused(
    const unsigned short* __restrict__ A,   // wo_h [256][512] bf16
    const unsigned short* __restrict__ Bt,  // attn_t (b,9216,512) bf16
    const float* __restrict__ g, const float* __restrict__ bb,
    const float* __restrict__ gamma, const float* __restrict__ qsrc,
    float* __restrict__ out)
{
    __shared__ unsigned short As[256 * 32];   // 16 KB
    __shared__ unsigned short Bs[64 * 32];    // 4 KB
    __shared__ float2 colred[4][64];          // 2 KB
    int b = blockIdx.z;
    const unsigned short* Bz = Bt + (size_t)b * 9216 * 512;
    int n0 = blockIdx.x * 64;
    int t = threadIdx.x;
    int w = t >> 6, l = t & 63;
    int lc = l & 15, quad = l >> 4;

    f32x4 acc[4][4];
    #pragma unroll
    for (int i = 0; i < 4; ++i)
        #pragma unroll
        for (int j = 0; j < 4; ++j) acc[i][j] = {0.f, 0.f, 0.f, 0.f};

    int srow = t >> 2, sseg = (t & 3) * 8;
    for (int k0 = 0; k0 < 512; k0 += 32) {
        __syncthreads();
        #pragma unroll
        for (int s = 0; s < 4; ++s)
            GL2LDS(A + (size_t)(s * 64 + srow) * 512 + k0 + sseg,
                   As + (size_t)s * 2048 + (size_t)t * 8);
        GL2LDS(Bz + (size_t)(n0 + srow) * 512 + k0 + sseg, Bs + (size_t)t * 8);
        __syncthreads();
        bf16x8 af[4], bfr[4];
        #pragma unroll
        for (int i = 0; i < 4; ++i)
            af[i] = *(const bf16x8*)(As + (size_t)(w * 64 + i * 16 + lc) * 32 + quad * 8);
        #pragma unroll
        for (int j = 0; j < 4; ++j)
            bfr[j] = *(const bf16x8*)(Bs + (size_t)(j * 16 + lc) * 32 + quad * 8);
        #pragma unroll
        for (int i = 0; i < 4; ++i)
            #pragma unroll
            for (int j = 0; j < 4; ++j)
                acc[i][j] = __builtin_amdgcn_mfma_f32_16x16x32_bf16(af[i], bfr[j], acc[i][j], 0, 0, 0);
    }

    float s_[4], ss_[4];
    #pragma unroll
    for (int j = 0; j < 4; ++j) {
        float s = 0.f, ss = 0.f;
        #pragma unroll
        for (int i = 0; i < 4; ++i)
            #pragma unroll
            for (int r = 0; r < 4; ++r) {
                float v = acc[i][j][r];
                s += v; ss += v * v;
            }
        s  += __shfl_xor(s, 16);  s  += __shfl_xor(s, 32);
        ss += __shfl_xor(ss, 16); ss += __shfl_xor(ss, 32);
        s_[j] = s; ss_[j] = ss;
    }
    if (quad == 0) {
        #pragma unroll
        for (int j = 0; j < 4; ++j) {
            colred[w][j * 16 + lc].x = s_[j];
            colred[w][j * 16 + lc].y = ss_[j];
        }
    }
    __syncthreads();
    float mean[4], inv[4];
    #pragma unroll
    for (int j = 0; j < 4; ++j) {
        float ts = 0.f, tss = 0.f;
        #pragma unroll
        for (int ww = 0; ww < 4; ++ww) {
            float2 v = colred[ww][j * 16 + lc];
            ts += v.x; tss += v.y;
        }
        float m = ts * (1.f / 256.f);
        float var = tss * (1.f / 256.f) - m * m;
        mean[j] = m;
        inv[j] = 1.f / sqrtf(var + EPSN);
    }
    float gm = gamma[0];
    const float* qsb = qsrc + (size_t)b * 256 * 9216;
    float* ob = out + (size_t)b * 256 * 9216;
    #pragma unroll
    for (int i = 0; i < 4; ++i)
        #pragma unroll
        for (int r = 0; r < 4; ++r) {
            int row = w * 64 + i * 16 + quad * 4 + r;
            float gg = g[row], bv = bb[row];
            #pragma unroll
            for (int j = 0; j < 4; ++j) {
                int col = n0 + j * 16 + lc;
                float v = (acc[i][j][r] - mean[j]) * inv[j] * gg + bv;
                ob[(size_t)row * 9216 + col] = gm * v + qsb[(size_t)row * 9216 + col];
            }
        }
}

// ---------------- top-8 row/col selection per bh -------------------------
__global__ void topk_kernel(const float* __restrict__ qprobe,
                            const float* __restrict__ krow,
                            const float* __restrict__ kcol,
                            int* __restrict__ toph, int* __restrict__ topw)
{
    int bh = blockIdx.x, t = threadIdx.x;  // 64 threads
    __shared__ float qp[64], sr[64], sc[64];
    qp[t] = qprobe[bh * 64 + t];
    __syncthreads();
    float s1 = 0.f, s2 = 0.f;
    for (int d = 0; d < 64; ++d) {
        float qv = qp[d];
        s1 += qv * krow[((size_t)bh * 64 + d) * 64 + t];
        s2 += qv * kcol[((size_t)bh * 64 + d) * 64 + t];
    }
    sr[t] = s1; sc[t] = s2;
    __syncthreads();
    if (t == 0) {
        unsigned long long used = 0ull;
        for (int it = 0; it < 8; ++it) {
            int best = -1; float bv = -INFINITY;
            for (int i = 0; i < 64; ++i)
                if (!((used >> i) & 1ull) && sr[i] > bv) { bv = sr[i]; best = i; }
            if (best < 0) best = it;
            used |= 1ull << best;
            toph[bh * 8 + it] = best;
        }
        used = 0ull;
        for (int it = 0; it < 8; ++it) {
            int best = -1; float bv = -INFINITY;
            for (int i = 0; i < 64; ++i)
                if (!((used >> i) & 1ull) && sc[i] > bv) { bv = sc[i]; best = i; }
            if (best < 0) best = it;
            used |= 1ull << best;
            topw[bh * 8 + it] = best;
        }
    }
}

// ---------------- gather pruned normalized K rows -> ksel [bh][t][d] -----
__global__ __launch_bounds__(256) void gather_k_kernel(
    const unsigned short* __restrict__ kn,
    const int* __restrict__ toph, const int* __restrict__ topw,
    unsigned short* __restrict__ ksel)
{
    int bh = blockIdx.x;
    __shared__ int th_s[8], tw_s[8];
    if (threadIdx.x < 8) th_s[threadIdx.x] = toph[bh * 8 + threadIdx.x];
    else if (threadIdx.x < 16) tw_s[threadIdx.x - 8] = topw[bh * 8 + threadIdx.x - 8];
    __syncthreads();
    int tok = threadIdx.x >> 2, sg = threadIdx.x & 3;   // 64 tok x 4 chunks
    int p = th_s[tok >> 3] * 64 + tw_s[tok & 7];
    const uint4* src = (const uint4*)(kn + ((size_t)bh * 4096 + p) * 64 + sg * 16);
    uint4* dst = (uint4*)(ksel + ((size_t)bh * 64 + tok) * 64 + sg * 16);
    dst[0] = src[0];
    dst[1] = src[1];
}

// ---------------- V at gathered positions -> bf16 transposed [bh][d][t] --
__global__ __launch_bounds__(256) void vsel_kernel(
    const float* __restrict__ w_kv, const unsigned short* __restrict__ ctxt,
    const int* __restrict__ toph, const int* __restrict__ topw,
    unsigned short* __restrict__ vt)
{
    int bh = blockIdx.x, b = bh >> 3, h = bh & 7;
    __shared__ int th_s[8], tw_s[8];
    if (threadIdx.x < 8) th_s[threadIdx.x] = toph[bh * 8 + threadIdx.x];
    else if (threadIdx.x < 16) tw_s[threadIdx.x - 8] = topw[bh * 8 + threadIdx.x - 8];
    __syncthreads();
    const unsigned short* cb = ctxt + (size_t)b * 4096 * 256;
    int l = blockIdx.y * 1024 + threadIdx.x;
    for (int it = 0; it < 4; ++it, l += 256) {
        int tok = l >> 6, d = l & 63;
        int p = th_s[tok >> 3] * 64 + tw_s[tok & 7];
        const float* wr = w_kv + (size_t)(512 + h * 64 + d) * 256;
        const unsigned short* cr = cb + (size_t)p * 256;
        float s = 0.f;
        for (int c = 0; c < 256; ++c) s += wr[c] * bf2f(cr[c]);
        vt[(size_t)bh * 4096 + d * 64 + tok] = f2bf(s);
    }
}

// ---------------- MFMA flash-style attention ------------------------------
#define LPAD 72
__global__ __launch_bounds__(256) void attn_mfma_kernel(
    const unsigned short* __restrict__ q_pd, const unsigned short* __restrict__ ksel,
    const unsigned short* __restrict__ vt, unsigned short* __restrict__ attn_t)
{
    int bh = blockIdx.y, b = bh >> 3, h = bh & 7;
    __shared__ unsigned short Ks[64 * LPAD];      // [t][d]
    __shared__ unsigned short Vs[64 * LPAD];      // [d][t]
    __shared__ unsigned short Ps[4][16 * LPAD];   // per-wave [p][t]
    int t = threadIdx.x, w = t >> 6, l = t & 63;
    int lc = l & 15, quad = l >> 4;
    {
        int r0 = t >> 3, c0 = (t & 7) * 8;        // rows 0..31
        const unsigned short* kg = ksel + (size_t)bh * 4096;
        const unsigned short* vg = vt + (size_t)bh * 4096;
        *(uint4*)(Ks + r0 * LPAD + c0)        = *(const uint4*)(kg + r0 * 64 + c0);
        *(uint4*)(Ks + (r0 + 32) * LPAD + c0) = *(const uint4*)(kg + (r0 + 32) * 64 + c0);
        *(uint4*)(Vs + r0 * LPAD + c0)        = *(const uint4*)(vg + r0 * 64 + c0);
        *(uint4*)(Vs + (r0 + 32) * LPAD + c0) = *(const uint4*)(vg + (r0 + 32) * 64 + c0);
    }
    __syncthreads();
    int p0 = blockIdx.x * 64 + w * 16;
    const unsigned short* qrow = q_pd + ((size_t)bh * 9216 + p0 + lc) * 64;
    bf16x8 aq0 = *(const bf16x8*)(qrow + quad * 8);
    bf16x8 aq1 = *(const bf16x8*)(qrow + 32 + quad * 8);
    f32x4 sacc[4];
    #pragma unroll
    for (int j = 0; j < 4; ++j) sacc[j] = {0.f, 0.f, 0.f, 0.f};
    #pragma unroll
    for (int j = 0; j < 4; ++j) {
        bf16x8 bk0 = *(const bf16x8*)(Ks + (j * 16 + lc) * LPAD + quad * 8);
        bf16x8 bk1 = *(const bf16x8*)(Ks + (j * 16 + lc) * LPAD + 32 + quad * 8);
        sacc[j] = __builtin_amdgcn_mfma_f32_16x16x32_bf16(aq0, bk0, sacc[j], 0, 0, 0);
        sacc[j] = __builtin_amdgcn_mfma_f32_16x16x32_bf16(aq1, bk1, sacc[j], 0, 0, 0);
    }
    float e[4][4], den[4] = {0.f, 0.f, 0.f, 0.f};
    #pragma unroll
    for (int j = 0; j < 4; ++j)
        #pragma unroll
        for (int r = 0; r < 4; ++r) {
            float v = __expf(sacc[j][r] - 1.f);
            e[j][r] = v; den[r] += v;
        }
    #pragma unroll
    for (int r = 0; r < 4; ++r) {
        den[r] += __shfl_xor(den[r], 1);
        den[r] += __shfl_xor(den[r], 2);
        den[r] += __shfl_xor(den[r], 4);
        den[r] += __shfl_xor(den[r], 8);
    }
    #pragma unroll
    for (int j = 0; j < 4; ++j)
        #pragma unroll
        for (int r = 0; r < 4; ++r)
            Ps[w][(quad * 4 + r) * LPAD + j * 16 + lc] = f2bf(e[j][r]);
    __syncthreads();
    bf16x8 ap0 = *(const bf16x8*)(Ps[w] + lc * LPAD + quad * 8);
    bf16x8 ap1 = *(const bf16x8*)(Ps[w] + lc * LPAD + 32 + quad * 8);
    f32x4 oacc[4];
    #pragma unroll
    for (int j = 0; j < 4; ++j) oacc[j] = {0.f, 0.f, 0.f, 0.f};
    #pragma unroll
    for (int j = 0; j < 4; ++j) {
        bf16x8 bv0 = *(const bf16x8*)(Vs + (j * 16 + lc) * LPAD + quad * 8);
        bf16x8 bv1 = *(const bf16x8*)(Vs + (j * 16 + lc) * LPAD + 32 + quad * 8);
        oacc[j] = __builtin_amdgcn_mfma_f32_16x16x32_bf16(ap0, bv0, oacc[j], 0, 0, 0);
        oacc[j] = __builtin_amdgcn_mfma_f32_16x16x32_bf16(ap1, bv1, oacc[j], 0, 0, 0);
    }
    float rd[4];
    #pragma unroll
    for (int r = 0; r < 4; ++r) rd[r] = 1.f / den[r];
    #pragma unroll
    for (int j = 0; j < 4; ++j)
        #pragma unroll
        for (int r = 0; r < 4; ++r) {
            int p = p0 + quad * 4 + r;
            int d = j * 16 + lc;
            attn_t[((size_t)b * 9216 + p) * 512 + h * 64 + d] = f2bf(oacc[j][r] * rd[r]);
        }
}

extern "C" void kernel_launch(void* const* d_in, const int* in_sizes, int n_in,
                              void* d_out, int out_size, void* d_ws, size_t ws_size,
                              hipStream_t stream) {
    const float* qsrc  = (const float*)d_in[0];
    const float* ctx   = (const float*)d_in[1];
    const float* qs_g  = (const float*)d_in[2];
    const float* qs_b  = (const float*)d_in[3];
    const float* ctx_g = (const float*)d_in[4];
    const float* ctx_b = (const float*)d_in[5];
    const float* out_g = (const float*)d_in[6];
    const float* out_b = (const float*)d_in[7];
    const float* w_q   = (const float*)d_in[8];
    const float* w_kv  = (const float*)d_in[9];
    const float* w_out = (const float*)d_in[10];
    const float* gamma = (const float*)d_in[11];
    float* out = (float*)d_out;

    // ---- workspace (bytes), liveness-aliased ----
    // Region A @0 (75,497,472): qs_h+qs_l [1-2]; kn@0 (33.5M) + kcolp@33.5M
    //   (33.5M) + krow@67.1M (1M) + kcol@68.2M (1M) [4-7]; attn_t [9-10]
    // Region B @75,497,472: q_pd bf16 (bh,9216,64) [2-9]
    // Region C @150,994,944: ctx_h+ctx_l [3-8]
    char* base = (char*)d_ws;
    unsigned short* qs_h  = (unsigned short*)(base + 0);
    unsigned short* qs_l  = (unsigned short*)(base + 37748736);
    unsigned short* kn    = (unsigned short*)(base + 0);
    float*          kcolp = (float*)        (base + 33554432);
    float*          krow  = (float*)        (base + 67108864);
    float*          kcol  = (float*)        (base + 68157440);
    unsigned short* attn_t= (unsigned short*)(base + 0);
    unsigned short* q_pd  = (unsigned short*)(base + 75497472);
    unsigned short* ctx_h = (unsigned short*)(base + 150994944);
    unsigned short* ctx_l = (unsigned short*)(base + 167772160);
    char* S = base + 184549376;
    float* qprob = (float*)S;                     S += 4096 * 4;
    unsigned short* ksel = (unsigned short*)S;    S += 262144 * 2;
    unsigned short* vt   = (unsigned short*)S;    S += 262144 * 2;
    int*   toph  = (int*)S;                       S += 512 * 4;
    int*   topw  = (int*)S;                       S += 512 * 4;
    unsigned short* wq_h = (unsigned short*)S;    S += 131072 * 2;
    unsigned short* wq_l = (unsigned short*)S;    S += 131072 * 2;
    unsigned short* wk_h = (unsigned short*)S;    S += 131072 * 2;
    unsigned short* wk_l = (unsigned short*)S;    S += 131072 * 2;
    unsigned short* wo_h = (unsigned short*)S;    S += 131072 * 2;

    // 0. weight splits
    cvt_split_kernel<<<512, 256, 0, stream>>>(w_q, wq_h, wq_l, 131072);
    cvt_split_kernel<<<512, 256, 0, stream>>>(w_kv, wk_h, wk_l, 131072);
    cvt_bf16_kernel<<<512, 256, 0, stream>>>(w_out, wo_h, 131072);
    hipMemsetAsync(qprob, 0, 4096 * sizeof(float), stream);
    // 1. qs hi/lo = chan_norm(query_source)^T
    chan_norm_split_kernel<<<288, 256, 0, stream>>>(qsrc, qs_g, qs_b, qs_h, qs_l, 9216);
    // 2. q = w_q @ qs -> q_pd normalized (bh,p,64) + qprobe
    gemm_x3<1><<<dim3(72, 4, 8), 256, 0, stream>>>(
        wq_h, wq_l, qs_h, qs_l, q_pd, qprob, nullptr, nullptr,
        512, 9216, 256, 9216LL * 256);
    // 3. ctx hi/lo = chan_norm(context)^T
    chan_norm_split_kernel<<<128, 256, 0, stream>>>(ctx, ctx_g, ctx_b, ctx_h, ctx_l, 4096);
    // 4. k = w_kv[0:512] @ ctx -> kn bf16 + fp32 krow/kcolp marginals
    gemm_x3<2><<<dim3(32, 4, 8), 256, 0, stream>>>(
        wk_h, wk_l, ctx_h, ctx_l, kn, nullptr, krow, kcolp,
        512, 4096, 256, 4096LL * 256);
    // 5. reduce kcol partials (32 segs)
    kcolred_kernel<<<dim3(64, 16), 256, 0, stream>>>(kcolp, kcol);
    // 6. top-8 rows/cols
    topk_kernel<<<64, 64, 0, stream>>>(qprob, krow, kcol, toph, topw);
    // 7. gather pruned K rows -> ksel [t][d]
    gather_k_kernel<<<64, 256, 0, stream>>>(kn, toph, topw, ksel);
    // 8. V at gathered positions -> bf16 [d][t]
    vsel_kernel<<<dim3(64, 4), 256, 0, stream>>>(w_kv, ctx_h, toph, topw, vt);
    // 9. MFMA attention -> attn_t bf16 (b,9216,512) (kn dead)
    attn_mfma_kernel<<<dim3(144, 64), 256, 0, stream>>>(q_pd, ksel, vt, attn_t);
    // 10. fused: out = chan_norm(w_out @ attn)*gamma + qsrc  (direct to d_out)
    gemm_out_fused<<<dim3(144, 1, 8), 256, 0, stream>>>(
        wo_h, attn_t, out_g, out_b, gamma, qsrc, out);
}